// Round 1
// baseline (869.752 us; speedup 1.0000x reference)
//
#include <hip/hip_runtime.h>

#define N_PTS 16384
#define CIN 128
#define COUT 256
#define KNN 20
#define NKTOT (N_PTS*KNN)
#define NEG_SLOPE 0.2f
#define BN_EPS 1e-5f

// ============================ KNN ============================
// 512 blocks x 256 threads. Block handles 32 queries, 8 threads/query.
// Thread-local top-20 (dist,idx) lists live in LDS (stride 21 to dodge banks).
// Candidate tiles of 256 points staged as float4(x,y,z,|p|^2).
__global__ __launch_bounds__(256) void knn_kernel(const float* __restrict__ pos,
                                                  int* __restrict__ out_idx)
{
    __shared__ float4 cand[256];
    __shared__ float  ld[256*21];
    __shared__ int    li[256*21];
    const float FINF = __builtin_inff();
    const int tid = threadIdx.x;
    const int r   = tid & 7;     // candidate sub-lane
    const int qi  = tid >> 3;    // query within block (0..31)
    const int i   = blockIdx.x*32 + qi;

    float* myd = &ld[tid*21];
    int*   myi = &li[tid*21];
#pragma unroll
    for (int s=0;s<KNN;s++){ myd[s]=FINF; myi[s]=0x7FFFFFFF; }
    float wd = FINF;   // current worst dist in my list
    int wslot = 0;

    const float xi = pos[i*3+0], yi = pos[i*3+1], zi = pos[i*3+2];
    const float sqi = xi*xi + yi*yi + zi*zi;

    for (int t=0;t<N_PTS/256;t++){
        __syncthreads();
        {
            const int p = t*256 + tid;
            const float cx = pos[p*3+0], cy = pos[p*3+1], cz = pos[p*3+2];
            cand[tid] = make_float4(cx,cy,cz, cx*cx+cy*cy+cz*cz);
        }
        __syncthreads();
#pragma unroll 4
        for (int s=0;s<32;s++){
            const int c = (s<<3) + r;
            const float4 cp = cand[c];
            const float dot = xi*cp.x + yi*cp.y + zi*cp.z;
            // match reference formula: sq_i + sq_j - 2*dot (f32)
            const float d = (sqi + cp.w) - 2.0f*dot;
            if (d < wd){                      // common path: 1 compare
                const int j = t*256 + c;
                if (j != i){                  // self-exclusion (rare path)
                    myd[wslot] = d; myi[wslot] = j;
                    wd = -FINF;
#pragma unroll
                    for (int s2=0;s2<KNN;s2++){
                        const float dv = myd[s2];
                        if (dv > wd){ wd = dv; wslot = s2; }
                    }
                }
            }
        }
    }
    __syncthreads();
    // merge the 8 per-thread lists of each query -> global top-20
    for (int round=0; round<KNN; ++round){
        float md = FINF; int mj = 0x7FFFFFFF; int ms = -1;
#pragma unroll
        for (int s=0;s<KNN;s++){
            const float dv = myd[s]; const int jv = myi[s];
            if (dv < md || (dv == md && jv < mj)){ md=dv; mj=jv; ms=s; }
        }
        float gd = md; int gj = mj;
#pragma unroll
        for (int off=1; off<8; off<<=1){     // butterfly over the 8 lanes of this query
            const float od = __shfl_xor(gd, off);
            const int   oj = __shfl_xor(gj, off);
            if (od < gd || (od == gd && oj < gj)){ gd = od; gj = oj; }
        }
        if (ms >= 0 && gd == md && gj == mj){ myd[ms] = FINF; myi[ms] = 0x7FFFFFFF; }
        if (r == 0) out_idx[i*KNN + round] = gj;
    }
}

// ============================ GEMM: A = x@W_top + b, B = x@W_bot ============================
// grid (256, 8): 64-row x 64-col tiles over M=16384, N'=512 (cols 0..255 -> A, 256..511 -> B).
// Block (0,0) also zero-inits the stats accumulators (ws is poisoned 0xAA each call).
__global__ __launch_bounds__(256) void gemm_kernel(const float* __restrict__ x,
                                                   const float* __restrict__ W,
                                                   const float* __restrict__ bias,
                                                   float* __restrict__ Aout,
                                                   float* __restrict__ Bout,
                                                   float* __restrict__ stats)
{
    if (blockIdx.x == 0 && blockIdx.y == 0){
        for (int s = threadIdx.x; s < 5*COUT; s += 256) stats[s] = 0.f;
    }
    __shared__ __align__(16) float xs[64][CIN+1];
    __shared__ __align__(16) float wt[CIN][64];
    const int tid = threadIdx.x;
    const int tx = tid & 15, ty = tid >> 4;
    const int m0 = blockIdx.x*64;
    const int n0 = blockIdx.y*64;

    for (int l=tid; l<64*CIN; l+=256){
        const int row = l >> 7, k = l & (CIN-1);
        xs[row][k] = x[(m0+row)*CIN + k];
    }
    for (int l=tid; l<CIN*64; l+=256){
        const int k = l >> 6, cc = l & 63;
        const int gc = n0 + cc;
        wt[k][cc] = (gc < COUT) ? W[k*COUT + gc] : W[(CIN+k)*COUT + (gc-COUT)];
    }
    __syncthreads();

    float acc[4][4] = {};
#pragma unroll 4
    for (int k=0;k<CIN;k++){
        const float a0 = xs[ty*4+0][k];
        const float a1 = xs[ty*4+1][k];
        const float a2 = xs[ty*4+2][k];
        const float a3 = xs[ty*4+3][k];
        const float4 bv = *(const float4*)&wt[k][tx*4];
        acc[0][0] += a0*bv.x; acc[0][1] += a0*bv.y; acc[0][2] += a0*bv.z; acc[0][3] += a0*bv.w;
        acc[1][0] += a1*bv.x; acc[1][1] += a1*bv.y; acc[1][2] += a1*bv.z; acc[1][3] += a1*bv.w;
        acc[2][0] += a2*bv.x; acc[2][1] += a2*bv.y; acc[2][2] += a2*bv.z; acc[2][3] += a2*bv.w;
        acc[3][0] += a3*bv.x; acc[3][1] += a3*bv.y; acc[3][2] += a3*bv.z; acc[3][3] += a3*bv.w;
    }
    const int colg = n0 + tx*4;
    if (colg < COUT){
        const float4 bb = *(const float4*)&bias[colg];
#pragma unroll
        for (int rr=0; rr<4; ++rr){
            const float4 v = make_float4(acc[rr][0]+bb.x, acc[rr][1]+bb.y,
                                         acc[rr][2]+bb.z, acc[rr][3]+bb.w);
            *(float4*)&Aout[(m0+ty*4+rr)*COUT + colg] = v;
        }
    } else {
        const int cb = colg - COUT;
#pragma unroll
        for (int rr=0; rr<4; ++rr){
            const float4 v = make_float4(acc[rr][0], acc[rr][1], acc[rr][2], acc[rr][3]);
            *(float4*)&Bout[(m0+ty*4+rr)*COUT + cb] = v;
        }
    }
}

// ============================ Gather + stats + SEL ============================
// 512 blocks x 256 threads: thread = channel c, block = 32 queries.
// h[i,k,c] = A[i,c] + B[idx[i,k],c]. We store SEL = A + (gamma>=0 ? max_k B : min_k B)
// (BN is per-channel affine, LeakyReLU monotone -> max/min commutes through).
// Stats: Σh = K·ΣA + ΣB ; Σh² = K·ΣA² + 2·Σ_i A·(Σ_k B) + ΣB².
__global__ __launch_bounds__(256) void gather_kernel(const int* __restrict__ idx,
        const float* __restrict__ A, const float* __restrict__ B,
        const float* __restrict__ gamma,
        float* __restrict__ sel, float* __restrict__ stats)
{
    __shared__ int sidx[32*KNN];
    const int c  = threadIdx.x;
    const int i0 = blockIdx.x*32;
    for (int l=c; l<32*KNN; l+=256) sidx[l] = idx[i0*KNN + l];
    __syncthreads();
    const float g = gamma[c];
    const float FINF = __builtin_inff();
    float sA=0.f, sA2=0.f, cross=0.f, sB=0.f, sB2=0.f;
    for (int ii=0; ii<32; ++ii){
        float bmax=-FINF, bmin=FINF, bsum=0.f;
#pragma unroll
        for (int k=0;k<KNN;k++){
            const int j = sidx[ii*KNN+k];        // wave-uniform -> coalesced 1KB row reads
            const float v = B[j*COUT + c];
            bmax = fmaxf(bmax, v);
            bmin = fminf(bmin, v);
            bsum += v;
            sB2 += v*v;
        }
        const int i = i0 + ii;
        const float a = A[i*COUT + c];
        sA += a; sA2 += a*a; cross += a*bsum; sB += bsum;
        sel[i*COUT + c] = a + (g >= 0.f ? bmax : bmin);
    }
    atomicAdd(&stats[0*COUT+c], sA);
    atomicAdd(&stats[1*COUT+c], sA2);
    atomicAdd(&stats[2*COUT+c], cross);
    atomicAdd(&stats[3*COUT+c], sB);
    atomicAdd(&stats[4*COUT+c], sB2);
}

// ============================ Finalize stats ============================
__global__ void finalize_kernel(const float* __restrict__ stats,
                                const float* __restrict__ gamma,
                                float* __restrict__ msc)
{
    const int c = threadIdx.x;
    const float sA  = stats[0*COUT+c];
    const float sA2 = stats[1*COUT+c];
    const float cr  = stats[2*COUT+c];
    const float sB  = stats[3*COUT+c];
    const float sB2 = stats[4*COUT+c];
    const float inv_nk = 1.0f / (float)NKTOT;
    const float mean = ((float)KNN*sA + sB) * inv_nk;
    const float eh2  = ((float)KNN*sA2 + 2.f*cr + sB2) * inv_nk;
    const float var  = eh2 - mean*mean;
    msc[c]        = mean;
    msc[COUT + c] = gamma[c] * rsqrtf(var + BN_EPS);
}

// ============================ BN + LeakyReLU (in place on d_out) ============================
__global__ __launch_bounds__(256) void out_kernel(float* __restrict__ sel_out,
                                                  const float* __restrict__ msc,
                                                  const float* __restrict__ beta)
{
    const int t = blockIdx.x*256 + threadIdx.x;
    const int base = t*4;
    const int c = base & (COUT-1);
    float4 v = *(const float4*)&sel_out[base];
    const float4 m  = *(const float4*)&msc[c];
    const float4 s  = *(const float4*)&msc[COUT + c];
    const float4 bt = *(const float4*)&beta[c];
    const float y0 = (v.x - m.x)*s.x + bt.x;
    const float y1 = (v.y - m.y)*s.y + bt.y;
    const float y2 = (v.z - m.z)*s.z + bt.z;
    const float y3 = (v.w - m.w)*s.w + bt.w;
    v.x = y0 >= 0.f ? y0 : NEG_SLOPE*y0;
    v.y = y1 >= 0.f ? y1 : NEG_SLOPE*y1;
    v.z = y2 >= 0.f ? y2 : NEG_SLOPE*y2;
    v.w = y3 >= 0.f ? y3 : NEG_SLOPE*y3;
    *(float4*)&sel_out[base] = v;
}

extern "C" void kernel_launch(void* const* d_in, const int* in_sizes, int n_in,
                              void* d_out, int out_size, void* d_ws, size_t ws_size,
                              hipStream_t stream)
{
    const float* pos   = (const float*)d_in[0];
    const float* x     = (const float*)d_in[1];
    const float* W     = (const float*)d_in[2];
    const float* bias  = (const float*)d_in[3];
    const float* gamma = (const float*)d_in[4];
    const float* beta  = (const float*)d_in[5];
    float* out = (float*)d_out;
    char*  ws  = (char*)d_ws;

    // ws layout: [idx 1.25MiB][A 16MiB][B 16MiB][stats ~7KiB]  (~34 MiB total)
    int*   idx   = (int*)(ws);
    float* A     = (float*)(ws + (2u<<20));
    float* Bm    = (float*)(ws + (2u<<20) + (16u<<20));
    float* stats = (float*)(ws + (2u<<20) + (32u<<20));
    float* msc   = stats + 5*COUT;

    knn_kernel     <<<dim3(512),    dim3(256), 0, stream>>>(pos, idx);
    gemm_kernel    <<<dim3(256, 8), dim3(256), 0, stream>>>(x, W, bias, A, Bm, stats);
    gather_kernel  <<<dim3(512),    dim3(256), 0, stream>>>(idx, A, Bm, gamma, out, stats);
    finalize_kernel<<<dim3(1),      dim3(256), 0, stream>>>(stats, gamma, msc);
    out_kernel     <<<dim3(4096),   dim3(256), 0, stream>>>(out, msc, beta);
}

// Round 3
// 697.019 us; speedup vs baseline: 1.2478x; 1.2478x over previous
//
#include <hip/hip_runtime.h>

#define N_PTS 16384
#define CIN 128
#define COUT 256
#define KNN 20
#define NKTOT (N_PTS*KNN)
#define NEG_SLOPE 0.2f
#define BN_EPS 1e-5f

// ============================ KNN ============================
// Wave-per-query. Block = 512 threads = 8 waves = 8 queries; grid = 2048.
// Unsorted exact top-20 in lanes 0..19 (one entry/lane), sentinel (+inf, MAXJ).
// Wave-uniform threshold = lex-max (worst) of the 20 entries. A candidate
// enters iff (d,j) <lex worst -> exact jax.lax.top_k set incl. tie-break.
// Insert = replace the worst's holder, recompute worst via lex-max butterfly.
// No sortedness/prefix invariants -- each insert re-derives state from scratch.
__global__ __launch_bounds__(512) void knn_kernel(const float* __restrict__ pos,
                                                  int* __restrict__ out_idx)
{
    __shared__ float4 cand[1024];
    const float FINF = __builtin_inff();
    const int tid  = threadIdx.x;
    const int lane = tid & 63;
    const int wv   = tid >> 6;              // wave in block, 0..7
    const int i    = blockIdx.x*8 + wv;     // my query

    const float xi = pos[i*3+0], yi = pos[i*3+1], zi = pos[i*3+2];
    const float sqi = xi*xi + yi*yi + zi*zi;

    float Ld = FINF; int Lj = 0x7FFFFFFF;   // my list slot (valid iff lane<KNN)
    float wd = FINF; int wj = 0x7FFFFFFF;   // current worst of the 20 (uniform)

    for (int ch = 0; ch < 16; ++ch){
        __syncthreads();
#pragma unroll
        for (int u = 0; u < 2; ++u){
            const int c = ch*1024 + u*512 + tid;
            const float cx = pos[c*3+0], cy = pos[c*3+1], cz = pos[c*3+2];
            cand[u*512 + tid] = make_float4(cx, cy, cz, cx*cx + cy*cy + cz*cz);
        }
        __syncthreads();

        for (int s = 0; s < 16; ++s){
            const float4 cp = cand[s*64 + lane];
            float d = (sqi + cp.w) - 2.0f*(xi*cp.x + yi*cp.y + zi*cp.z);
            int   j = ch*1024 + s*64 + lane;
            if (j == i){ d = FINF; j = 0x7FFFFFFF; }   // self: sentinel, never enters

            const bool q = (d < wd) || (d == wd && j < wj);
            unsigned long long mask = __ballot(q);
            while (mask){
                const int src = (int)__builtin_ctzll(mask);
                mask &= mask - 1;
                const float dn = __shfl(d, src);
                const int   jn = __shfl(j, src);
                if ((dn < wd) || (dn == wd && jn < wj)){   // recheck vs tightened worst
                    // exactly one list lane holds (wd,wj) among lanes<KNN except
                    // during sentinel fill (all match) -> take lowest matching lane
                    const bool match = (lane < KNN) && (Ld == wd) && (Lj == wj);
                    const unsigned long long mm = __ballot(match);
                    if (lane == (int)__builtin_ctzll(mm)){ Ld = dn; Lj = jn; }
                    // recompute worst = lex-max over lanes 0..KNN-1 (all < 32):
                    // 5-stage xor butterfly over the low 32-lane group, then bcast.
                    float md = (lane < KNN) ? Ld : -FINF;
                    int   mj = (lane < KNN) ? Lj : -1;
#pragma unroll
                    for (int off = 16; off > 0; off >>= 1){
                        const float od = __shfl_xor(md, off);
                        const int   oj = __shfl_xor(mj, off);
                        if (od > md || (od == md && oj > mj)){ md = od; mj = oj; }
                    }
                    wd = __shfl(md, 0); wj = __shfl(mj, 0);
                }
            }
        }
    }
    if (lane < KNN) out_idx[i*KNN + lane] = Lj;
}

// ============================ GEMM: A = x@W_top + b, B = x@W_bot ============================
__global__ __launch_bounds__(256) void gemm_kernel(const float* __restrict__ x,
                                                   const float* __restrict__ W,
                                                   const float* __restrict__ bias,
                                                   float* __restrict__ Aout,
                                                   float* __restrict__ Bout,
                                                   float* __restrict__ stats)
{
    if (blockIdx.x == 0 && blockIdx.y == 0){
        for (int s = threadIdx.x; s < 5*COUT; s += 256) stats[s] = 0.f;
    }
    __shared__ __align__(16) float xs[64][CIN+1];
    __shared__ __align__(16) float wt[CIN][64];
    const int tid = threadIdx.x;
    const int tx = tid & 15, ty = tid >> 4;
    const int m0 = blockIdx.x*64;
    const int n0 = blockIdx.y*64;

    for (int l=tid; l<64*CIN; l+=256){
        const int row = l >> 7, k = l & (CIN-1);
        xs[row][k] = x[(m0+row)*CIN + k];
    }
    for (int l=tid; l<CIN*64; l+=256){
        const int k = l >> 6, cc = l & 63;
        const int gc = n0 + cc;
        wt[k][cc] = (gc < COUT) ? W[k*COUT + gc] : W[(CIN+k)*COUT + (gc-COUT)];
    }
    __syncthreads();

    float acc[4][4] = {};
#pragma unroll 4
    for (int k=0;k<CIN;k++){
        const float a0 = xs[ty*4+0][k];
        const float a1 = xs[ty*4+1][k];
        const float a2 = xs[ty*4+2][k];
        const float a3 = xs[ty*4+3][k];
        const float4 bv = *(const float4*)&wt[k][tx*4];
        acc[0][0] += a0*bv.x; acc[0][1] += a0*bv.y; acc[0][2] += a0*bv.z; acc[0][3] += a0*bv.w;
        acc[1][0] += a1*bv.x; acc[1][1] += a1*bv.y; acc[1][2] += a1*bv.z; acc[1][3] += a1*bv.w;
        acc[2][0] += a2*bv.x; acc[2][1] += a2*bv.y; acc[2][2] += a2*bv.z; acc[2][3] += a2*bv.w;
        acc[3][0] += a3*bv.x; acc[3][1] += a3*bv.y; acc[3][2] += a3*bv.z; acc[3][3] += a3*bv.w;
    }
    const int colg = n0 + tx*4;
    if (colg < COUT){
        const float4 bb = *(const float4*)&bias[colg];
#pragma unroll
        for (int rr=0; rr<4; ++rr){
            const float4 v = make_float4(acc[rr][0]+bb.x, acc[rr][1]+bb.y,
                                         acc[rr][2]+bb.z, acc[rr][3]+bb.w);
            *(float4*)&Aout[(m0+ty*4+rr)*COUT + colg] = v;
        }
    } else {
        const int cb = colg - COUT;
#pragma unroll
        for (int rr=0; rr<4; ++rr){
            const float4 v = make_float4(acc[rr][0], acc[rr][1], acc[rr][2], acc[rr][3]);
            *(float4*)&Bout[(m0+ty*4+rr)*COUT + cb] = v;
        }
    }
}

// ============================ Gather + stats + SEL ============================
__global__ __launch_bounds__(256) void gather_kernel(const int* __restrict__ idx,
        const float* __restrict__ A, const float* __restrict__ B,
        const float* __restrict__ gamma,
        float* __restrict__ sel, float* __restrict__ stats)
{
    __shared__ int sidx[32*KNN];
    const int c  = threadIdx.x;
    const int i0 = blockIdx.x*32;
    for (int l=c; l<32*KNN; l+=256) sidx[l] = idx[i0*KNN + l];
    __syncthreads();
    const float g = gamma[c];
    const float FINF = __builtin_inff();
    float sA=0.f, sA2=0.f, cross=0.f, sB=0.f, sB2=0.f;
    for (int ii=0; ii<32; ++ii){
        float bmax=-FINF, bmin=FINF, bsum=0.f;
#pragma unroll
        for (int k=0;k<KNN;k++){
            const int j = sidx[ii*KNN+k];        // wave-uniform -> coalesced 1KB row reads
            const float v = B[j*COUT + c];
            bmax = fmaxf(bmax, v);
            bmin = fminf(bmin, v);
            bsum += v;
            sB2 += v*v;
        }
        const int i = i0 + ii;
        const float a = A[i*COUT + c];
        sA += a; sA2 += a*a; cross += a*bsum; sB += bsum;
        sel[i*COUT + c] = a + (g >= 0.f ? bmax : bmin);
    }
    atomicAdd(&stats[0*COUT+c], sA);
    atomicAdd(&stats[1*COUT+c], sA2);
    atomicAdd(&stats[2*COUT+c], cross);
    atomicAdd(&stats[3*COUT+c], sB);
    atomicAdd(&stats[4*COUT+c], sB2);
}

// ============================ Finalize stats ============================
__global__ void finalize_kernel(const float* __restrict__ stats,
                                const float* __restrict__ gamma,
                                float* __restrict__ msc)
{
    const int c = threadIdx.x;
    const float sA  = stats[0*COUT+c];
    const float sA2 = stats[1*COUT+c];
    const float cr  = stats[2*COUT+c];
    const float sB  = stats[3*COUT+c];
    const float sB2 = stats[4*COUT+c];
    const float inv_nk = 1.0f / (float)NKTOT;
    const float mean = ((float)KNN*sA + sB) * inv_nk;
    const float eh2  = ((float)KNN*sA2 + 2.f*cr + sB2) * inv_nk;
    const float var  = eh2 - mean*mean;
    msc[c]        = mean;
    msc[COUT + c] = gamma[c] * rsqrtf(var + BN_EPS);
}

// ============================ BN + LeakyReLU (in place on d_out) ============================
__global__ __launch_bounds__(256) void out_kernel(float* __restrict__ sel_out,
                                                  const float* __restrict__ msc,
                                                  const float* __restrict__ beta)
{
    const int t = blockIdx.x*256 + threadIdx.x;
    const int base = t*4;
    const int c = base & (COUT-1);
    float4 v = *(const float4*)&sel_out[base];
    const float4 m  = *(const float4*)&msc[c];
    const float4 s  = *(const float4*)&msc[COUT + c];
    const float4 bt = *(const float4*)&beta[c];
    const float y0 = (v.x - m.x)*s.x + bt.x;
    const float y1 = (v.y - m.y)*s.y + bt.y;
    const float y2 = (v.z - m.z)*s.z + bt.z;
    const float y3 = (v.w - m.w)*s.w + bt.w;
    v.x = y0 >= 0.f ? y0 : NEG_SLOPE*y0;
    v.y = y1 >= 0.f ? y1 : NEG_SLOPE*y1;
    v.z = y2 >= 0.f ? y2 : NEG_SLOPE*y2;
    v.w = y3 >= 0.f ? y3 : NEG_SLOPE*y3;
    *(float4*)&sel_out[base] = v;
}

extern "C" void kernel_launch(void* const* d_in, const int* in_sizes, int n_in,
                              void* d_out, int out_size, void* d_ws, size_t ws_size,
                              hipStream_t stream)
{
    const float* pos   = (const float*)d_in[0];
    const float* x     = (const float*)d_in[1];
    const float* W     = (const float*)d_in[2];
    const float* bias  = (const float*)d_in[3];
    const float* gamma = (const float*)d_in[4];
    const float* beta  = (const float*)d_in[5];
    float* out = (float*)d_out;
    char*  ws  = (char*)d_ws;

    // ws layout: [idx 1.25MiB][A 16MiB][B 16MiB][stats ~7KiB]  (~34 MiB total)
    int*   idx   = (int*)(ws);
    float* A     = (float*)(ws + (2u<<20));
    float* Bm    = (float*)(ws + (2u<<20) + (16u<<20));
    float* stats = (float*)(ws + (2u<<20) + (32u<<20));
    float* msc   = stats + 5*COUT;

    knn_kernel     <<<dim3(2048),   dim3(512), 0, stream>>>(pos, idx);
    gemm_kernel    <<<dim3(256, 8), dim3(256), 0, stream>>>(x, W, bias, A, Bm, stats);
    gather_kernel  <<<dim3(512),    dim3(256), 0, stream>>>(idx, A, Bm, gamma, out, stats);
    finalize_kernel<<<dim3(1),      dim3(256), 0, stream>>>(stats, gamma, msc);
    out_kernel     <<<dim3(4096),   dim3(256), 0, stream>>>(out, msc, beta);
}